// Round 9
// baseline (178.509 us; speedup 1.0000x reference)
//
#include <hip/hip_runtime.h>
#include <math.h>

// Problem constants (B=64, S=8192, D=32), fp32 in/out.
#define B_ 64
#define S_ 8192
#define D_ 32

__device__ __forceinline__ void load_lds16(const float* g, float* l) {
    __builtin_amdgcn_global_load_lds(
        (const __attribute__((address_space(1))) void*)g,
        (__attribute__((address_space(3))) void*)l,
        16, 0, 0);
}

// ---------------- Kernel 1: per-batch Gram matrix G = x^T x ----------------
// (byte-identical to the PASSING round-7 kernel)
#define GCH 16

__global__ __launch_bounds__(256, 8) void gram_k(const float* __restrict__ x,
                                                 float* __restrict__ gpart) {
    __shared__ float tile[128 * D_];        // 16 KB
    const int blk = blockIdx.x;             // 1024
    const int b   = blk >> 4;
    const int ch  = blk & 15;
    const int t   = threadIdx.x;
    const int w   = t >> 6;
    const int l   = t & 63;
    const int i0  = ((l >> 3) & 7) << 2;    // 0,4,...,28
    const int j0  = (l & 7) << 2;

    const float* xb = x + ((size_t)b * S_ + (size_t)ch * 512) * D_;

    float acc[4][4] = {};
    for (int s = 0; s < 4; ++s) {
        const float* src = xb + (size_t)s * 128 * D_;
        #pragma unroll
        for (int k = 0; k < 4; ++k) {
            const int g = k * 256 + t;      // linear granule 0..1023
            load_lds16(src + g * 4, tile + g * 4);
        }
        __syncthreads();                    // compiler drains vmcnt before barrier

        #pragma unroll 4
        for (int it = 0; it < 32; ++it) {
            const int r = w * 32 + it;      // wave-private rows
            const float* row = tile + r * D_;
            const float4 xi = *(const float4*)(row + i0);
            const float4 xj = *(const float4*)(row + j0);
            const float xiv[4] = {xi.x, xi.y, xi.z, xi.w};
            const float xjv[4] = {xj.x, xj.y, xj.z, xj.w};
            #pragma unroll
            for (int a = 0; a < 4; ++a)
                #pragma unroll
                for (int c = 0; c < 4; ++c)
                    acc[a][c] = fmaf(xiv[a], xjv[c], acc[a][c]);
        }
        __syncthreads();                    // before overwriting tile
    }

    // Cross-wave reduce: red[4][1024] reuses tile (exactly 16 KB).
    float* red = tile;
    #pragma unroll
    for (int a = 0; a < 4; ++a)
        #pragma unroll
        for (int c = 0; c < 4; ++c)
            red[w * 1024 + l * 16 + a * 4 + c] = acc[a][c];
    __syncthreads();

    #pragma unroll
    for (int e4 = 0; e4 < 4; ++e4) {
        const int e = e4 * 256 + t;
        const float sv = red[e] + red[1024 + e] + red[2048 + e] + red[3072 + e];
        const int ll = e >> 4, ee = e & 15;
        const int i = (((ll >> 3) & 7) << 2) + (ee >> 2);
        const int j = ((ll & 7) << 2) + (ee & 3);
        gpart[(size_t)blk * 1024 + i * 32 + j] = sv;
    }
}

// ------------- Kernel 2: tiny per-batch scores/softmax and M ---------------
// (byte-identical to rounds 2-7, always passed)
__global__ __launch_bounds__(1024) void attn_small(const float* __restrict__ gpart,
                                                   const float* __restrict__ Wq,
                                                   const float* __restrict__ Wk,
                                                   const float* __restrict__ Wv,
                                                   float* __restrict__ M) {
    __shared__ float GL[32][33], WqL[32][33], WkL[32][33], WvL[32][33];
    __shared__ float T1L[32][33], PL[32][33];
    __shared__ float mcol[32], scol[32];

    const int b = blockIdx.x;
    const int t = threadIdx.x;
    const int r = t >> 5, c = t & 31;

    float g = 0.f;
    #pragma unroll
    for (int cc = 0; cc < GCH; ++cc)
        g += gpart[(size_t)(b * GCH + cc) * 1024 + t];
    GL[r][c]  = g;
    WqL[r][c] = Wq[t];
    WkL[r][c] = Wk[t];
    WvL[r][c] = Wv[t];
    __syncthreads();

    float t1 = 0.f;
    #pragma unroll
    for (int e = 0; e < 32; ++e) t1 = fmaf(GL[r][e], WkL[e][c], t1);
    T1L[r][c] = t1;
    __syncthreads();

    float p = 0.f;
    #pragma unroll
    for (int d = 0; d < 32; ++d) p = fmaf(WqL[d][r], T1L[d][c], p);
    PL[r][c] = p;
    __syncthreads();

    if (t < 32) {
        float m = -INFINITY;
        #pragma unroll
        for (int q = 0; q < 32; ++q) m = fmaxf(m, PL[q][t]);
        float s = 0.f;
        #pragma unroll
        for (int q = 0; q < 32; ++q) s += __expf(PL[q][t] - m);
        mcol[t] = m;
        scol[t] = 1.0f / s;
    }
    __syncthreads();
    const float sc = __expf(PL[r][c] - mcol[c]) * scol[c];
    PL[r][c] = sc;
    __syncthreads();

    float mm = 0.f;
    #pragma unroll
    for (int k = 0; k < 32; ++k) mm = fmaf(WvL[r][k], PL[c][k], mm);
    M[(size_t)b * 1024 + t] = mm;    // M[b][d][q]
}

// ---------------- Kernel 3: out[b][q][s] = sum_d x[b][s][d] * M[b][d][q] ----
// 2048 blocks (b, ch of 256 rows) x 128 thr, 32 KB LDS (5 blocks/CU).
// Each lane computes TWO consecutive s (rows 2t, 2t+1) -> float2 stores:
// one wave store instruction now covers 512 B contiguous per q (was 256 B
// scalar), doubling the DRAM write run length. Stage/read swizzle identical
// to the passing round-3/4/7 math (involution c ^= r&7 on 16 B granules),
// extended to 256 rows.
__global__ __launch_bounds__(128, 2) void out_k(const float* __restrict__ x,
                                                const float* __restrict__ M,
                                                float* __restrict__ out) {
    __shared__ float tile[256 * D_];        // 32 KB
    const int blk = blockIdx.x;             // 2048
    const int b   = blk >> 5;
    const int ch  = blk & 31;
    const int t   = threadIdx.x;

    const float* src = x + ((size_t)b * S_ + (size_t)ch * 256) * D_;
    #pragma unroll
    for (int k = 0; k < 16; ++k) {
        const int g = k * 128 + t;          // linear LDS granule 0..2047
        const int r = g >> 3, c = g & 7;    // r: 0..255
        const int sg = r * 8 + (c ^ (r & 7));
        load_lds16(src + sg * 4, tile + g * 4);
    }
    __syncthreads();                        // vmcnt(0) drain + block sync

    const float* Mb = M + (size_t)b * 1024;
    float acc0[32] = {}, acc1[32] = {};
    const int r0 = 2 * t, r1 = 2 * t + 1;
    #pragma unroll
    for (int j = 0; j < 8; ++j) {
        const int pg0 = r0 * 8 + (j ^ (r0 & 7));
        const int pg1 = r1 * 8 + (j ^ (r1 & 7));
        const float4 xv0 = *(const float4*)(tile + pg0 * 4);
        const float4 xv1 = *(const float4*)(tile + pg1 * 4);
        const float xd0[4] = {xv0.x, xv0.y, xv0.z, xv0.w};
        const float xd1[4] = {xv1.x, xv1.y, xv1.z, xv1.w};
        #pragma unroll
        for (int dd = 0; dd < 4; ++dd) {
            const int d = j * 4 + dd;
            #pragma unroll
            for (int q = 0; q < 32; ++q) {
                const float m = Mb[d * 32 + q];
                acc0[q] = fmaf(m, xd0[dd], acc0[q]);
                acc1[q] = fmaf(m, xd1[dd], acc1[q]);
            }
        }
    }

    const int s = ch * 256 + 2 * t;
    float* ob = out + (size_t)b * D_ * S_ + s;
    #pragma unroll
    for (int q = 0; q < 32; ++q)
        *(float2*)(ob + (size_t)q * S_) = make_float2(acc0[q], acc1[q]);
}

extern "C" void kernel_launch(void* const* d_in, const int* in_sizes, int n_in,
                              void* d_out, int out_size, void* d_ws, size_t ws_size,
                              hipStream_t stream) {
    const float* x  = (const float*)d_in[0];
    const float* Wq = (const float*)d_in[1];
    const float* Wk = (const float*)d_in[2];
    const float* Wv = (const float*)d_in[3];
    float* out = (float*)d_out;

    // ws layout: gpart[1024][1024] (4 MiB) then M[64][1024] (256 KiB).
    float* gpart = (float*)d_ws;
    float* M     = gpart + (size_t)B_ * GCH * 1024;

    gram_k<<<B_ * GCH, 256, 0, stream>>>(x, gpart);
    attn_small<<<B_, 1024, 0, stream>>>(gpart, Wq, Wk, Wv, M);
    out_k<<<B_ * 32, 128, 0, stream>>>(x, M, out);
}